// Round 3
// baseline (638.560 us; speedup 1.0000x reference)
//
#include <hip/hip_runtime.h>
#include <hip/hip_bf16.h>

// DirectEncodingModel: B=16384, IN=512; 3 hidden group-layers (G=64,F=24,O=16)
// gather-from-growing-acc + tanh, then head (GO_G=4,GO_F=48,GO_O=16).
// acc cols per row: [0,512)=x, [512,1536)=L1, [1536,2560)=L2, [2560,3584)=L3.
// All float tensors fp32; idx int32; out fp32 (16384x64).
//
// R3: latency-bound fix. 512 thr/block, thread=(g, r) one row. Prefetch idx
// (int4 x6) then all 24 gathers as independent ds_read_u16, then dense
// unrolled FMA with pipelined weight float4 loads. 2 blocks/CU (LDS-limited),
// 16 waves/CU.

typedef unsigned short ushort_t;
typedef unsigned int uint_t;

#define ROWS_PER_BLOCK 8
#define BLOCK_THREADS 512
#define ACC_COLS 3584

__device__ __forceinline__ float bf2f(ushort_t u) {
    union { uint_t i; float f; } v;
    v.i = ((uint_t)u) << 16;
    return v.f;
}

__device__ __forceinline__ ushort_t f2bf(float f) {
    union { float f; uint_t i; } v;
    v.f = f;
    uint_t x = v.i;
    uint_t r = (x + 0x7fffu + ((x >> 16) & 1u)) >> 16;  // RNE; inputs finite
    return (ushort_t)r;
}

__device__ __forceinline__ uint_t pack2bf(float lo, float hi) {
    return (uint_t)f2bf(lo) | ((uint_t)f2bf(hi) << 16);
}

__device__ __forceinline__ float fast_tanh(float x) {
    float cx = fminf(fmaxf(x, -9.0f), 9.0f);
    float e = __expf(2.0f * cx);
    return (e - 1.0f) * __builtin_amdgcn_rcpf(e + 1.0f);
}

__global__ __launch_bounds__(BLOCK_THREADS, 4)
void demodel_kernel(const float* __restrict__ x,
                    const float* __restrict__ W1, const float* __restrict__ b1,
                    const float* __restrict__ W2, const float* __restrict__ b2,
                    const float* __restrict__ W3, const float* __restrict__ b3,
                    const float* __restrict__ Wo, const float* __restrict__ bo,
                    const int* __restrict__ idx1, const int* __restrict__ idx2,
                    const int* __restrict__ idx3, const int* __restrict__ idxo,
                    float* __restrict__ out)
{
    // 8 rows x 3584 cols, bf16: 57344 bytes -> 2 blocks/CU
    __shared__ __align__(16) ushort_t acc[ROWS_PER_BLOCK][ACC_COLS];

    const int t = threadIdx.x;
    const int row0 = blockIdx.x * ROWS_PER_BLOCK;
    const int g = t & 63;   // group (hidden layers) / out-col (head)
    const int r = t >> 6;   // row 0..7

    // ---- Phase 0: stage x tile (8 rows x 512 fp32) into LDS as bf16 ----
    {
        const int c = g << 3;   // 8 floats per thread
        const float4* src = reinterpret_cast<const float4*>(x + (size_t)(row0 + r) * 512 + c);
        float4 v0 = src[0];
        float4 v1 = src[1];
        uint4 p;
        p.x = pack2bf(v0.x, v0.y); p.y = pack2bf(v0.z, v0.w);
        p.z = pack2bf(v1.x, v1.y); p.w = pack2bf(v1.z, v1.w);
        *reinterpret_cast<uint4*>(&acc[r][c]) = p;
    }
    __syncthreads();

    // ---- Hidden layers: thread owns (group g, row r) ----
    const float* Wl[3] = { W1, W2, W3 };
    const float* bl[3] = { b1, b2, b3 };
    const int* il[3] = { idx1, idx2, idx3 };

    int out_base = 512;
    #pragma unroll
    for (int l = 0; l < 3; ++l) {
        // 1) prefetch 24 indices (independent int4 loads; base 96B-aligned)
        const int4* ip = reinterpret_cast<const int4*>(il[l] + g * 24);
        int ix[24];
        #pragma unroll
        for (int q = 0; q < 6; ++q) {
            int4 v = ip[q];
            ix[q * 4 + 0] = v.x;
            ix[q * 4 + 1] = v.y;
            ix[q * 4 + 2] = v.z;
            ix[q * 4 + 3] = v.w;
        }

        // 2) issue all 24 gathers (independent ds_read_u16)
        float av[24];
        #pragma unroll
        for (int f = 0; f < 24; ++f)
            av[f] = bf2f(acc[r][ix[f]]);

        // 3) bias init
        const float* bb = bl[l] + g * 16;
        const float4* bp = reinterpret_cast<const float4*>(bb);
        float4 bv0 = bp[0], bv1 = bp[1], bv2 = bp[2], bv3 = bp[3];
        float s_[16] = { bv0.x, bv0.y, bv0.z, bv0.w,
                         bv1.x, bv1.y, bv1.z, bv1.w,
                         bv2.x, bv2.y, bv2.z, bv2.w,
                         bv3.x, bv3.y, bv3.z, bv3.w };

        // 4) dense FMA block; weight loads are address-independent -> pipeline
        const float* W = Wl[l] + g * 384;   // g*24*16
        #pragma unroll
        for (int f = 0; f < 24; ++f) {
            const float4* wp = reinterpret_cast<const float4*>(W + f * 16);
            float4 wa = wp[0], wb = wp[1], wc = wp[2], wd = wp[3];
            const float a = av[f];
            s_[0]  = fmaf(a, wa.x, s_[0]);  s_[1]  = fmaf(a, wa.y, s_[1]);
            s_[2]  = fmaf(a, wa.z, s_[2]);  s_[3]  = fmaf(a, wa.w, s_[3]);
            s_[4]  = fmaf(a, wb.x, s_[4]);  s_[5]  = fmaf(a, wb.y, s_[5]);
            s_[6]  = fmaf(a, wb.z, s_[6]);  s_[7]  = fmaf(a, wb.w, s_[7]);
            s_[8]  = fmaf(a, wc.x, s_[8]);  s_[9]  = fmaf(a, wc.y, s_[9]);
            s_[10] = fmaf(a, wc.z, s_[10]); s_[11] = fmaf(a, wc.w, s_[11]);
            s_[12] = fmaf(a, wd.x, s_[12]); s_[13] = fmaf(a, wd.y, s_[13]);
            s_[14] = fmaf(a, wd.z, s_[14]); s_[15] = fmaf(a, wd.w, s_[15]);
        }

        // 5) tanh + pack + store 32 B
        uint4 q0, q1;
        q0.x = pack2bf(fast_tanh(s_[0]),  fast_tanh(s_[1]));
        q0.y = pack2bf(fast_tanh(s_[2]),  fast_tanh(s_[3]));
        q0.z = pack2bf(fast_tanh(s_[4]),  fast_tanh(s_[5]));
        q0.w = pack2bf(fast_tanh(s_[6]),  fast_tanh(s_[7]));
        q1.x = pack2bf(fast_tanh(s_[8]),  fast_tanh(s_[9]));
        q1.y = pack2bf(fast_tanh(s_[10]), fast_tanh(s_[11]));
        q1.z = pack2bf(fast_tanh(s_[12]), fast_tanh(s_[13]));
        q1.w = pack2bf(fast_tanh(s_[14]), fast_tanh(s_[15]));
        uint4* d = reinterpret_cast<uint4*>(&acc[r][out_base + g * 16]);
        d[0] = q0;
        d[1] = q1;

        out_base += 1024;
        __syncthreads();
    }

    // ---- Head: thread = (col j = g, row r); 48-long dot ----
    {
        const int go = g >> 4;         // 0..3
        const int oo = g & 15;         // 0..15

        const int4* ip = reinterpret_cast<const int4*>(idxo + go * 48);
        int ix[48];
        #pragma unroll
        for (int q = 0; q < 12; ++q) {
            int4 v = ip[q];
            ix[q * 4 + 0] = v.x;
            ix[q * 4 + 1] = v.y;
            ix[q * 4 + 2] = v.z;
            ix[q * 4 + 3] = v.w;
        }

        float av[48];
        #pragma unroll
        for (int f = 0; f < 48; ++f)
            av[f] = bf2f(acc[r][ix[f]]);

        const float* W = Wo + go * 768;   // go*48*16
        float sum = bo[go * 16 + oo];
        #pragma unroll
        for (int f = 0; f < 48; ++f)
            sum = fmaf(av[f], W[f * 16 + oo], sum);

        out[(size_t)(row0 + r) * 64 + g] = sum;
    }
}

extern "C" void kernel_launch(void* const* d_in, const int* in_sizes, int n_in,
                              void* d_out, int out_size, void* d_ws, size_t ws_size,
                              hipStream_t stream) {
    const float* x  = (const float*)d_in[0];
    const float* W1 = (const float*)d_in[1];
    const float* b1 = (const float*)d_in[2];
    const float* W2 = (const float*)d_in[3];
    const float* b2 = (const float*)d_in[4];
    const float* W3 = (const float*)d_in[5];
    const float* b3 = (const float*)d_in[6];
    const float* Wo = (const float*)d_in[7];
    const float* bo = (const float*)d_in[8];
    const int* idx1 = (const int*)d_in[9];
    const int* idx2 = (const int*)d_in[10];
    const int* idx3 = (const int*)d_in[11];
    const int* idxo = (const int*)d_in[12];
    float* out = (float*)d_out;

    const int B = in_sizes[0] / 512;            // 16384
    const int grid = B / ROWS_PER_BLOCK;        // 2048

    demodel_kernel<<<grid, BLOCK_THREADS, 0, stream>>>(
        x, W1, b1, W2, b2, W3, b3, Wo, bo, idx1, idx2, idx3, idxo, out);
}

// Round 4
// 147.577 us; speedup vs baseline: 4.3270x; 4.3270x over previous
//
#include <hip/hip_runtime.h>

// DirectEncodingModel via MFMA: per group, (16 rows x 24) @ (24x16) is ONE
// v_mfma_f32_16x16x32_bf16 (K zero-padded 24->32). Block = 512 thr (8 waves)
// owns a 16-row acc tile in dynamic LDS (16 x 3592 bf16 = 112 KB; cols
// [3584,3592) are a zero pad that K-padding gathers point at). Wave w does
// groups [8w, 8w+8) per layer. Weights are pre-packed to B-fragment order
// (bf16, K zero-padded) in d_ws by convert_weights so the inner-loop B load
// is one coalesced dwordx4 per lane.
// Layouts: A[m=lane&15][k=(lane>>4)*8+j] (m120-verified);
//          B[k=(lane>>4)*8+j][n=lane&15];
//          C/D: col=lane&15, row=(lane>>4)*4+reg (m89-verified).

typedef unsigned short ushort_t;
typedef unsigned int uint_t;
typedef __attribute__((ext_vector_type(8))) short short8;   // 8 bf16 frag
typedef __attribute__((ext_vector_type(4))) float f32x4;    // MFMA acc

#define ACC_STRIDE 3592
#define ZERO_COL 3584
#define LDS_BYTES (16 * ACC_STRIDE * 2)   // 114944 B

__device__ __forceinline__ ushort_t f2bf(float f) {
    union { float f; uint_t i; } v;
    v.f = f;
    uint_t x = v.i;
    uint_t r = (x + 0x7fffu + ((x >> 16) & 1u)) >> 16;  // RNE; inputs finite
    return (ushort_t)r;
}

__device__ __forceinline__ uint_t pack2bf(float lo, float hi) {
    return (uint_t)f2bf(lo) | ((uint_t)f2bf(hi) << 16);
}

__device__ __forceinline__ float fast_tanh(float x) {
    float cx = fminf(fmaxf(x, -9.0f), 9.0f);
    float e = __expf(2.0f * cx);
    return (e - 1.0f) * __builtin_amdgcn_rcpf(e + 1.0f);
}

// ---- Pre-pack weights to B-frag order, fp32 -> bf16, zero-pad K ----
// hidden: entry tid in [0,12288): (l,g,lane) -> 8 u16 at wfrag + tid*8
//         value j = W_l[g][k=(lane>>4)*8+j][n=lane&15], 0 if k>=24
// head:   tid in [12288,12800): h=(go*2+step)*64+lane,
//         value j = Wo[go][k=step*32+(lane>>4)*8+j][n], 0 if k>=48
__global__ __launch_bounds__(256)
void convert_weights(const float* __restrict__ W1, const float* __restrict__ W2,
                     const float* __restrict__ W3, const float* __restrict__ Wo,
                     ushort_t* __restrict__ wfrag)
{
    const int tid = blockIdx.x * 256 + threadIdx.x;
    const int lane = tid & 63;
    const int nn = lane & 15;
    const int quad = lane >> 4;
    ushort_t v[8];
    if (tid < 12288) {
        const int g = (tid >> 6) & 63;
        const int l = tid >> 12;   // 0..2
        const float* W = (l == 0) ? W1 : (l == 1) ? W2 : W3;
        const float* Wg = W + g * 384;
        #pragma unroll
        for (int j = 0; j < 8; ++j) {
            const int k = quad * 8 + j;
            v[j] = (k < 24) ? f2bf(Wg[k * 16 + nn]) : (ushort_t)0;
        }
    } else if (tid < 12800) {
        const int h = tid - 12288;
        const int gs = h >> 6;          // 0..7
        const int go = gs >> 1;
        const int step = gs & 1;
        const float* Wg = Wo + go * 768;
        #pragma unroll
        for (int j = 0; j < 8; ++j) {
            const int k = step * 32 + quad * 8 + j;
            v[j] = (k < 48) ? f2bf(Wg[k * 16 + nn]) : (ushort_t)0;
        }
    } else {
        return;
    }
    ushort4* dst = reinterpret_cast<ushort4*>(wfrag + (size_t)tid * 8);
    dst[0] = make_ushort4(v[0], v[1], v[2], v[3]);
    dst[1] = make_ushort4(v[4], v[5], v[6], v[7]);
}

__global__ __launch_bounds__(512)
void demodel_mfma(const float* __restrict__ x,
                  const float* __restrict__ b1, const float* __restrict__ b2,
                  const float* __restrict__ b3, const float* __restrict__ bo,
                  const ushort_t* __restrict__ wfrag,
                  const int* __restrict__ idx1, const int* __restrict__ idx2,
                  const int* __restrict__ idx3, const int* __restrict__ idxo,
                  float* __restrict__ out)
{
    extern __shared__ ushort_t smem[];   // 16 x ACC_STRIDE bf16
    const int t = threadIdx.x;
    const int lane = t & 63;
    const int wv = t >> 6;               // wave 0..7
    const int row0 = blockIdx.x * 16;
    const int nn = lane & 15;
    const int quad = lane >> 4;
    const bool q3 = (quad == 3);

    // ---- stage x: 16 rows x 512 fp32 -> LDS bf16; zero the pad cols ----
    {
        const int r = t >> 5;            // 0..15
        const int c = (t & 31) << 4;     // 16 floats per thread
        const float4* src = reinterpret_cast<const float4*>(
            x + (size_t)(row0 + r) * 512 + c);
        float4 a0 = src[0], a1 = src[1], a2 = src[2], a3 = src[3];
        uint4 p0, p1;
        p0.x = pack2bf(a0.x, a0.y); p0.y = pack2bf(a0.z, a0.w);
        p0.z = pack2bf(a1.x, a1.y); p0.w = pack2bf(a1.z, a1.w);
        p1.x = pack2bf(a2.x, a2.y); p1.y = pack2bf(a2.z, a2.w);
        p1.z = pack2bf(a3.x, a3.y); p1.w = pack2bf(a3.z, a3.w);
        uint4* dst = reinterpret_cast<uint4*>(smem + r * ACC_STRIDE + c);
        dst[0] = p0;
        dst[1] = p1;
        if (t < 16) {
            *reinterpret_cast<uint4*>(smem + t * ACC_STRIDE + ZERO_COL) =
                make_uint4(0u, 0u, 0u, 0u);
        }
    }
    __syncthreads();

    const ushort_t* acc_row = smem + nn * ACC_STRIDE;   // A row m = lane&15

    const int* il[3] = { idx1, idx2, idx3 };
    const float* bl[3] = { b1, b2, b3 };

    #pragma unroll 1
    for (int l = 0; l < 3; ++l) {
        const int* idxl = il[l];
        const float* bb = bl[l];
        const int out_base = 512 + l * 1024;
        #pragma unroll 1
        for (int gi = 0; gi < 8; ++gi) {
            const int g = wv * 8 + gi;
            // indices for this lane's 8 k-values (quad3 = K-pad -> zero col)
            const int ib = g * 24 + (q3 ? 0 : quad * 8);
            const int4 i0 = *reinterpret_cast<const int4*>(idxl + ib);
            const int4 i1 = *reinterpret_cast<const int4*>(idxl + ib + 4);
            // gather A fragment from LDS
            short8 af;
            af[0] = (short)acc_row[q3 ? ZERO_COL : i0.x];
            af[1] = (short)acc_row[q3 ? ZERO_COL : i0.y];
            af[2] = (short)acc_row[q3 ? ZERO_COL : i0.z];
            af[3] = (short)acc_row[q3 ? ZERO_COL : i0.w];
            af[4] = (short)acc_row[q3 ? ZERO_COL : i1.x];
            af[5] = (short)acc_row[q3 ? ZERO_COL : i1.y];
            af[6] = (short)acc_row[q3 ? ZERO_COL : i1.z];
            af[7] = (short)acc_row[q3 ? ZERO_COL : i1.w];
            // B fragment: one coalesced 16B load
            const short8 bf = *reinterpret_cast<const short8*>(
                wfrag + (((size_t)l * 64 + g) * 64 + lane) * 8);
            const float bv = bb[g * 16 + nn];
            f32x4 acc = { bv, bv, bv, bv };
            acc = __builtin_amdgcn_mfma_f32_16x16x32_bf16(af, bf, acc, 0, 0, 0);
            // epilogue: tanh -> bf16 -> acc tile
            const int colo = out_base + g * 16 + nn;
            #pragma unroll
            for (int i = 0; i < 4; ++i)
                smem[(quad * 4 + i) * ACC_STRIDE + colo] = f2bf(fast_tanh(acc[i]));
        }
        __syncthreads();
    }

    // ---- head: waves 0..3, go = wv; K=48 -> 2 MFMA steps (pad to 64) ----
    if (wv < 4) {
        const int go = wv;
        const float bv = bo[go * 16 + nn];
        f32x4 acc = { bv, bv, bv, bv };
        #pragma unroll
        for (int step = 0; step < 2; ++step) {
            const int kb = step * 32 + quad * 8;
            const bool ok = (kb < 48);           // whole 8-chunk valid or pad
            const int ib = go * 48 + (ok ? kb : 0);
            const int4 i0 = *reinterpret_cast<const int4*>(idxo + ib);
            const int4 i1 = *reinterpret_cast<const int4*>(idxo + ib + 4);
            short8 af;
            af[0] = (short)acc_row[ok ? i0.x : ZERO_COL];
            af[1] = (short)acc_row[ok ? i0.y : ZERO_COL];
            af[2] = (short)acc_row[ok ? i0.z : ZERO_COL];
            af[3] = (short)acc_row[ok ? i0.w : ZERO_COL];
            af[4] = (short)acc_row[ok ? i1.x : ZERO_COL];
            af[5] = (short)acc_row[ok ? i1.y : ZERO_COL];
            af[6] = (short)acc_row[ok ? i1.z : ZERO_COL];
            af[7] = (short)acc_row[ok ? i1.w : ZERO_COL];
            const short8 bf = *reinterpret_cast<const short8*>(
                wfrag + (12288 + ((size_t)go * 2 + step) * 64 + lane) * 8);
            acc = __builtin_amdgcn_mfma_f32_16x16x32_bf16(af, bf, acc, 0, 0, 0);
        }
        #pragma unroll
        for (int i = 0; i < 4; ++i)
            out[(size_t)(row0 + quad * 4 + i) * 64 + go * 16 + nn] = acc[i];
    }
}

extern "C" void kernel_launch(void* const* d_in, const int* in_sizes, int n_in,
                              void* d_out, int out_size, void* d_ws, size_t ws_size,
                              hipStream_t stream) {
    const float* x  = (const float*)d_in[0];
    const float* W1 = (const float*)d_in[1];
    const float* b1 = (const float*)d_in[2];
    const float* W2 = (const float*)d_in[3];
    const float* b2 = (const float*)d_in[4];
    const float* W3 = (const float*)d_in[5];
    const float* b3 = (const float*)d_in[6];
    const float* Wo = (const float*)d_in[7];
    const float* bo = (const float*)d_in[8];
    const int* idx1 = (const int*)d_in[9];
    const int* idx2 = (const int*)d_in[10];
    const int* idx3 = (const int*)d_in[11];
    const int* idxo = (const int*)d_in[12];
    float* out = (float*)d_out;

    (void)hipFuncSetAttribute((const void*)demodel_mfma,
                              hipFuncAttributeMaxDynamicSharedMemorySize,
                              LDS_BYTES);

    // pack weights into d_ws (204,800 B used)
    convert_weights<<<50, 256, 0, stream>>>(W1, W2, W3, Wo, (ushort_t*)d_ws);

    const int B = in_sizes[0] / 512;   // 16384
    const int grid = B / 16;           // 1024
    demodel_mfma<<<grid, 512, LDS_BYTES, stream>>>(
        x, b1, b2, b3, bo, (const ushort_t*)d_ws,
        idx1, idx2, idx3, idxo, out);
}

// Round 5
// 127.146 us; speedup vs baseline: 5.0222x; 1.1607x over previous
//
#include <hip/hip_runtime.h>
#include <hip/hip_bf16.h>

// DirectEncodingModel via MFMA. Per group, (16 rows x 24) @ (24x16) is ONE
// v_mfma_f32_16x16x32_bf16 (K zero-padded 24->32). Block = 1024 thr (16
// waves) owns a 16-row acc tile in dynamic LDS; wave w does 4 groups/layer.
// convert_weights pre-packs (a) weights in B-fragment order (bf16, K-padded)
// and (b) gather BYTE-offset tables in fragment order with the K-pad already
// substituted (points at a zeroed pad column), so the inner loop is pure
// ds_read_b128 (offsets) -> v_add x8 -> ds_read_u16 x8 -> MFMA -> tanh.
// Layouts (HW-verified): A[m=lane&15][k=(lane>>4)*8+j];
//   B[k=(lane>>4)*8+j][n=lane&15]; C/D col=lane&15, row=(lane>>4)*4+reg.

typedef unsigned short ushort_t;
typedef unsigned int uint_t;
typedef __attribute__((ext_vector_type(8))) short short8;   // 8 bf16 frag
typedef __attribute__((ext_vector_type(4))) float f32x4;    // MFMA acc

#define ACC_STRIDE 3592                   // u16 per row (8-col zero pad)
#define ZERO_COL 3584
#define ACC_U16 (16 * ACC_STRIDE)         // 57472 u16 = 114944 B
#define OFFS_BYTES 25600                  // hidden 24576 + head 1024
#define LDS_BYTES (ACC_U16 * 2 + OFFS_BYTES)   // 140544 B

// d_ws layout (bytes)
#define WF_HEAD_B 196608                  // 12288*16
#define OFF_HID_B 204800                  // +512*16
#define OFF_HEAD_B 229376                 // +6144*4

__device__ __forceinline__ ushort_t f2bf(float f) {
    // hardware fptrunc f32->bf16 (RNE on gfx950)
    __hip_bfloat16 h = __float2bfloat16(f);
    union { __hip_bfloat16 h; ushort_t u; } v;
    v.h = h;
    return v.u;
}

__device__ __forceinline__ uint_t pack2bf(float lo, float hi) {
    return (uint_t)f2bf(lo) | ((uint_t)f2bf(hi) << 16);
}

// tanh(x) = 1 - 2/(e^2x + 1); exp saturation gives exact +-1 tails, no clamp.
__device__ __forceinline__ float fast_tanh(float x) {
    float e = __expf(2.0f * x);
    return fmaf(-2.0f, __builtin_amdgcn_rcpf(e + 1.0f), 1.0f);
}

// ---- Pre-pack weights (B-frag order, bf16, K zero-padded) + offset tables --
__global__ __launch_bounds__(256)
void convert_weights(const float* __restrict__ W1, const float* __restrict__ W2,
                     const float* __restrict__ W3, const float* __restrict__ Wo,
                     const int* __restrict__ idx1, const int* __restrict__ idx2,
                     const int* __restrict__ idx3, const int* __restrict__ idxo,
                     ushort_t* __restrict__ ws)
{
    const int tid = blockIdx.x * 256 + threadIdx.x;
    const int lane = tid & 63;
    const int nn = lane & 15;
    const int quad = lane >> 4;
    if (tid < 12288) {
        const int g = (tid >> 6) & 63;
        const int l = tid >> 12;   // 0..2
        const float* W = (l == 0) ? W1 : (l == 1) ? W2 : W3;
        const float* Wg = W + g * 384;
        ushort_t v[8];
        #pragma unroll
        for (int j = 0; j < 8; ++j) {
            const int k = quad * 8 + j;
            v[j] = (k < 24) ? f2bf(Wg[k * 16 + nn]) : (ushort_t)0;
        }
        ushort4* dst = reinterpret_cast<ushort4*>(ws + (size_t)tid * 8);
        dst[0] = make_ushort4(v[0], v[1], v[2], v[3]);
        dst[1] = make_ushort4(v[4], v[5], v[6], v[7]);
    } else if (tid < 12800) {
        const int h = tid - 12288;
        const int gs = h >> 6;          // 0..7: go*2+step
        const int go = gs >> 1;
        const int step = gs & 1;
        const float* Wg = Wo + go * 768;
        ushort_t v[8];
        #pragma unroll
        for (int j = 0; j < 8; ++j) {
            const int k = step * 32 + quad * 8 + j;
            v[j] = (k < 48) ? f2bf(Wg[k * 16 + nn]) : (ushort_t)0;
        }
        ushort4* dst = reinterpret_cast<ushort4*>(ws + (size_t)tid * 8);
        dst[0] = make_ushort4(v[0], v[1], v[2], v[3]);
        dst[1] = make_ushort4(v[4], v[5], v[6], v[7]);
    } else if (tid < 18944) {
        // hidden gather byte-offsets, frag order: e = l*2048 + g*32 + k
        const int e = tid - 12800;
        const int l = e >> 11;
        const int rem = e & 2047;
        const int g = rem >> 5;
        const int k = rem & 31;
        const int* idx = (l == 0) ? idx1 : (l == 1) ? idx2 : idx3;
        const int v = (k < 24) ? idx[g * 24 + k] * 2 : ZERO_COL * 2;
        reinterpret_cast<int*>((char*)ws + OFF_HID_B)[e] = v;
    } else if (tid < 19200) {
        // head gather byte-offsets: e = go*64 + k (k zero-padded 48->64)
        const int e = tid - 18944;
        const int go = e >> 6;
        const int k = e & 63;
        const int v = (k < 48) ? idxo[go * 48 + k] * 2 : ZERO_COL * 2;
        reinterpret_cast<int*>((char*)ws + OFF_HEAD_B)[e] = v;
    }
}

__global__ __launch_bounds__(1024)
void demodel_mfma(const float* __restrict__ x,
                  const float* __restrict__ b1, const float* __restrict__ b2,
                  const float* __restrict__ b3, const float* __restrict__ bo,
                  const ushort_t* __restrict__ ws,
                  float* __restrict__ out)
{
    extern __shared__ __align__(16) ushort_t smem[];
    const int t = threadIdx.x;
    const int lane = t & 63;
    const int wv = t >> 6;               // wave 0..15
    const int row0 = blockIdx.x * 16;
    const int nn = lane & 15;
    const int quad = lane >> 4;

    // ---- stage x: 16 rows x 512 fp32 -> LDS bf16 ----
    {
        const int r = t >> 6;            // 0..15
        const int c = (t & 63) << 3;     // 0..504, 8 floats per thread
        const float4* src = reinterpret_cast<const float4*>(
            x + (size_t)(row0 + r) * 512 + c);
        float4 a0 = src[0], a1 = src[1];
        uint4 p;
        p.x = pack2bf(a0.x, a0.y); p.y = pack2bf(a0.z, a0.w);
        p.z = pack2bf(a1.x, a1.y); p.w = pack2bf(a1.z, a1.w);
        *reinterpret_cast<uint4*>(smem + r * ACC_STRIDE + c) = p;
    }
    if (t < 16)   // zero the pad columns each gather's K-pad points at
        *reinterpret_cast<uint4*>(smem + t * ACC_STRIDE + ZERO_COL) =
            make_uint4(0u, 0u, 0u, 0u);
    // ---- stage offset tables: 25600 B global -> LDS ----
    {
        const uint4* src = reinterpret_cast<const uint4*>((const char*)ws + OFF_HID_B);
        uint4* dst = reinterpret_cast<uint4*>(smem + ACC_U16);
        for (int i = t; i < OFFS_BYTES / 16; i += 1024)
            dst[i] = src[i];
    }
    __syncthreads();

    const int* offs = reinterpret_cast<const int*>(smem + ACC_U16);
    const char* accb = (const char*)smem + nn * (ACC_STRIDE * 2);  // A row m=nn

    #pragma unroll 1
    for (int l = 0; l < 3; ++l) {
        const float* bb = (l == 0) ? b1 : (l == 1) ? b2 : b3;
        const int out_base = 512 + l * 1024;
        #pragma unroll 2
        for (int gi = 0; gi < 4; ++gi) {
            const int g = (wv << 2) + gi;
            const int* op = offs + l * 2048 + g * 32 + quad * 8;
            const int4 o0 = *reinterpret_cast<const int4*>(op);
            const int4 o1 = *reinterpret_cast<const int4*>(op + 4);
            short8 af;
            af[0] = *(const short*)(accb + o0.x);
            af[1] = *(const short*)(accb + o0.y);
            af[2] = *(const short*)(accb + o0.z);
            af[3] = *(const short*)(accb + o0.w);
            af[4] = *(const short*)(accb + o1.x);
            af[5] = *(const short*)(accb + o1.y);
            af[6] = *(const short*)(accb + o1.z);
            af[7] = *(const short*)(accb + o1.w);
            const short8 bf = *reinterpret_cast<const short8*>(
                ws + (((size_t)l * 64 + g) * 64 + lane) * 8);
            const float bv = bb[g * 16 + nn];
            f32x4 acc = { bv, bv, bv, bv };
            acc = __builtin_amdgcn_mfma_f32_16x16x32_bf16(af, bf, acc, 0, 0, 0);
            const int colo = out_base + g * 16 + nn;
            #pragma unroll
            for (int i = 0; i < 4; ++i)
                smem[(quad * 4 + i) * ACC_STRIDE + colo] = f2bf(fast_tanh(acc[i]));
        }
        __syncthreads();
    }

    // ---- head: waves 0..3, go = wv; K=48 -> 2 MFMA steps (pad to 64) ----
    if (wv < 4) {
        const int go = wv;
        const float bv = bo[go * 16 + nn];
        f32x4 acc = { bv, bv, bv, bv };
        #pragma unroll
        for (int s = 0; s < 2; ++s) {
            const int* op = offs + 6144 + go * 64 + s * 32 + quad * 8;
            const int4 o0 = *reinterpret_cast<const int4*>(op);
            const int4 o1 = *reinterpret_cast<const int4*>(op + 4);
            short8 af;
            af[0] = *(const short*)(accb + o0.x);
            af[1] = *(const short*)(accb + o0.y);
            af[2] = *(const short*)(accb + o0.z);
            af[3] = *(const short*)(accb + o0.w);
            af[4] = *(const short*)(accb + o1.x);
            af[5] = *(const short*)(accb + o1.y);
            af[6] = *(const short*)(accb + o1.z);
            af[7] = *(const short*)(accb + o1.w);
            const short8 bf = *reinterpret_cast<const short8*>(
                ws + (12288 + ((size_t)go * 2 + s) * 64 + lane) * 8);
            acc = __builtin_amdgcn_mfma_f32_16x16x32_bf16(af, bf, acc, 0, 0, 0);
        }
        #pragma unroll
        for (int i = 0; i < 4; ++i)
            out[(size_t)(row0 + quad * 4 + i) * 64 + go * 16 + nn] = acc[i];
    }
}

extern "C" void kernel_launch(void* const* d_in, const int* in_sizes, int n_in,
                              void* d_out, int out_size, void* d_ws, size_t ws_size,
                              hipStream_t stream) {
    const float* x  = (const float*)d_in[0];
    const float* W1 = (const float*)d_in[1];
    const float* b1 = (const float*)d_in[2];
    const float* W2 = (const float*)d_in[3];
    const float* b2 = (const float*)d_in[4];
    const float* W3 = (const float*)d_in[5];
    const float* b3 = (const float*)d_in[6];
    const float* Wo = (const float*)d_in[7];
    const float* bo = (const float*)d_in[8];
    const int* idx1 = (const int*)d_in[9];
    const int* idx2 = (const int*)d_in[10];
    const int* idx3 = (const int*)d_in[11];
    const int* idxo = (const int*)d_in[12];
    float* out = (float*)d_out;

    (void)hipFuncSetAttribute((const void*)demodel_mfma,
                              hipFuncAttributeMaxDynamicSharedMemorySize,
                              LDS_BYTES);

    convert_weights<<<75, 256, 0, stream>>>(W1, W2, W3, Wo,
                                            idx1, idx2, idx3, idxo,
                                            (ushort_t*)d_ws);

    const int B = in_sizes[0] / 512;   // 16384
    const int grid = B / 16;           // 1024
    demodel_mfma<<<grid, 1024, LDS_BYTES, stream>>>(
        x, b1, b2, b3, bo, (const ushort_t*)d_ws, out);
}